// Round 18
// baseline (155.415 us; speedup 1.0000x reference)
//
#include <hip/hip_runtime.h>
#include <math.h>

#define B_    128
#define C_    768
#define O_    192
#define HW_   289
#define N_IN  (128*768*289)
#define N_OUT (128*192*289)
#define QN_   127.0f

#define SLAB_SH  9248               // shorts per pooled slab (289*32)
#define SLAB_BYT 18496              // bytes per pooled slab; codes at +9248
#define AB_BLOCKS 2048              // absmax blocks in fused pre-kernel

typedef __attribute__((ext_vector_type(4))) int i32x4;

// XOR swizzle within a 64B row: flip 16B-chunk bits (4..5) by row bits (6..7). Involution.
#define SWZ(b) ((b) ^ ((((b) >> 6) & 3) << 4))

// ws layout:
//  0     : cnt[0]=absmax(x) bits, cnt[1]=max|pooled| int, cnt[2]=absmax(out) bits
//  4096  : f32 wsf_g[192]
//  5120  : f32 bf_g[192]
//  8192  : i8 w_q8 image, [kt64][o][64c] linear, 12*12288 B
//  1MiB  : per-slab 18496B regions: [0,9248) pooled i16 (written by k_pool),
//          [9248,18496) int8 codes (written by k_quant, consumed+overwritten by k_pool)

// Fused: blocks 0..2047 absmax(x); blocks 2048..2239 weight-quant (independent).
__global__ void k_pre(const float4* __restrict__ x4, int n4,
                      const float* __restrict__ conv_w,
                      const float* __restrict__ g,
                      const float* __restrict__ beta,
                      const float* __restrict__ mu,
                      const float* __restrict__ var,
                      signed char* __restrict__ w_q8,
                      float* __restrict__ wsf_g, float* __restrict__ bf_g,
                      unsigned* cnt) {
    if (blockIdx.x < AB_BLOCKS) {
        float m = 0.f;
        const int stride = AB_BLOCKS * blockDim.x;
        int i = blockIdx.x * blockDim.x + threadIdx.x;
        for (; i + stride < n4; i += 2 * stride) {
            float4 v = x4[i];
            float4 w = x4[i + stride];
            m = fmaxf(m, fmaxf(fmaxf(fabsf(v.x), fabsf(v.y)),
                               fmaxf(fabsf(v.z), fabsf(v.w))));
            m = fmaxf(m, fmaxf(fmaxf(fabsf(w.x), fabsf(w.y)),
                               fmaxf(fabsf(w.z), fabsf(w.w))));
        }
        if (i < n4) {
            float4 v = x4[i];
            m = fmaxf(m, fmaxf(fmaxf(fabsf(v.x), fabsf(v.y)),
                               fmaxf(fabsf(v.z), fabsf(v.w))));
        }
#pragma unroll
        for (int off = 32; off; off >>= 1) m = fmaxf(m, __shfl_down(m, off));
        __shared__ float sm[4];
        int lane = threadIdx.x & 63, wv = threadIdx.x >> 6;
        if (lane == 0) sm[wv] = m;
        __syncthreads();
        if (threadIdx.x == 0) {
            float bm = fmaxf(fmaxf(sm[0], sm[1]), fmaxf(sm[2], sm[3]));
            atomicMax(cnt + 0, __float_as_uint(bm));
        }
        return;
    }
    const int o = blockIdx.x - AB_BLOCKS;   // 0..191
    const float stdv = sqrtf(var[o] + 1e-5f);
    const float r = g[o] / stdv;
    const float* wo = conv_w + o * C_;
    float m = 0.f;
    for (int c = threadIdx.x; c < C_; c += 256) m = fmaxf(m, fabsf(wo[c] * r));
#pragma unroll
    for (int off = 32; off; off >>= 1) m = fmaxf(m, __shfl_down(m, off));
    __shared__ float sm2[4];
    __shared__ float swsf;
    int lane = threadIdx.x & 63, wv = threadIdx.x >> 6;
    if (lane == 0) sm2[wv] = m;
    __syncthreads();
    if (threadIdx.x == 0) {
        float bm = fmaxf(fmaxf(sm2[0], sm2[1]), fmaxf(sm2[2], sm2[3]));
        swsf = fmaxf(bm / QN_, 1e-8f);
    }
    __syncthreads();
    const float wsf = swsf;
    for (int c = threadIdx.x; c < C_; c += 256) {
        float wi = rintf(wo[c] * r / wsf);
        wi = fminf(fmaxf(wi, -128.f), 127.f);
        w_q8[(c >> 6) * 12288 + o * 64 + (c & 63)] = (signed char)(int)wi;
    }
    if (threadIdx.x == 0) {
        wsf_g[o] = wsf;
        bf_g[o] = beta[o] - g[o] * mu[o] / stdv;
    }
}

// Streaming quant: x -> int8 codes rintf(x/s0), stored into each slab's code half.
__global__ void k_quant(const float4* __restrict__ x4, char* __restrict__ pbase,
                        const unsigned* __restrict__ cnt) {
    const float s0 = fmaxf(__uint_as_float(cnt[0]) / QN_, 1e-8f);
    const int n4 = N_IN / 4;
    for (int t = blockIdx.x * blockDim.x + threadIdx.x; t < n4;
         t += gridDim.x * blockDim.x) {
        float4 v = x4[t];
        int q0 = (int)rintf(v.x / s0);
        int q1 = (int)rintf(v.y / s0);
        int q2 = (int)rintf(v.z / s0);
        int q3 = (int)rintf(v.w / s0);
        int e = 4 * t;
        unsigned gp = (unsigned)e / 289u;       // global plane
        int hw = e - (int)gp * 289;
        if (hw <= 285) {
            size_t off = (size_t)(gp >> 5) * SLAB_BYT + 9248 + (gp & 31) * 289 + hw;
            unsigned pk = (q0 & 0xff) | ((q1 & 0xff) << 8) | ((q2 & 0xff) << 16) |
                          ((unsigned)(q3 & 0xff) << 24);
            *(unsigned*)(pbase + off) = pk;     // proven 4B-aligned
        } else {
            int qs0 = q0, qs1 = q1, qs2 = q2, qs3 = q3;
#pragma unroll
            for (int j = 0; j < 4; ++j) {
                int qv = (j == 0) ? qs0 : (j == 1) ? qs1 : (j == 2) ? qs2 : qs3;
                int ej = e + j;
                unsigned gj = (unsigned)ej / 289u;
                int hwj = ej - (int)gj * 289;
                size_t oj = (size_t)(gj >> 5) * SLAB_BYT + 9248 + (gj & 31) * 289 + hwj;
                pbase[oj] = (char)qv;
            }
        }
    }
}

// Pool: block = one slab of 32 planes. Stage 9248B codes into LDS, 3x3 sum with
// row/col masking (replaces zero-padding), coalesced i16 stores overwrite region.
__launch_bounds__(256) __global__
void k_pool(short* __restrict__ pooled, unsigned* cnt) {
    __shared__ __align__(4) char sq[4 + 9248 + 12];   // front pad 4, tail pad 12
    __shared__ int smax[4];
    const int tid = threadIdx.x;
    const int s = blockIdx.x;               // slab 0..3071
    char* region = (char*)pooled + (size_t)s * SLAB_BYT;

    // stage codes (b32, both sides 4B-aligned)
    {
        const unsigned* src = (const unsigned*)(region + 9248);
        unsigned* dst = (unsigned*)(sq + 4);
        for (int i = tid; i < 2312; i += 256) dst[i] = src[i];
    }
    if (tid < 4) *(unsigned*)(sq + tid * 4 * 0) = 0;   // zero front pad word (tid==0)
    if (tid < 3) *(unsigned*)(sq + 4 + 9248 + tid * 4) = 0;  // zero tail pad
    __syncthreads();

    auto load6 = [&](int off, int& b0, int& b1, int& b2, int& b3, int& b4,
                     int& b5) {
        int al = off & ~3;
        const char* base = sq + 4 + al;
        unsigned w0 = *(const unsigned*)(base);
        unsigned w1 = *(const unsigned*)(base + 4);
        unsigned w2 = *(const unsigned*)(base + 8);
        int sh = off & 3;
        unsigned long long lo = (unsigned long long)w0 |
                                ((unsigned long long)w1 << 32);
        unsigned long long v = lo >> (8 * sh);
        b0 = (int)(signed char)(v);
        b1 = (int)(signed char)(v >> 8);
        b2 = (int)(signed char)(v >> 16);
        b3 = (int)(signed char)(v >> 24);
        b4 = (int)(signed char)(v >> 32);
        b5 = (sh == 3) ? (int)(signed char)w2 : (int)(signed char)(v >> 40);
    };

    short* slab16 = pooled + (size_t)s * SLAB_SH;
    int tmax = 0;
    for (int task = tid; task < 2720; task += 256) {
        int p = task & 31;
        int rt = task >> 5;                 // 0..84
        int r = (rt * 3277) >> 14;          // rt/5
        int t5 = rt - r * 5;
        int c0 = t5 * 4;
        int rowbase = p * 289 + c0 - 1;
        int cs0 = 0, cs1 = 0, cs2 = 0, cs3 = 0, cs4 = 0, cs5 = 0;
        {
            int b0, b1, b2, b3, b4, b5;
            if (r > 0) {
                load6(rowbase + (r - 1) * 17, b0, b1, b2, b3, b4, b5);
                cs0 += b0; cs1 += b1; cs2 += b2; cs3 += b3; cs4 += b4; cs5 += b5;
            }
            load6(rowbase + r * 17, b0, b1, b2, b3, b4, b5);
            cs0 += b0; cs1 += b1; cs2 += b2; cs3 += b3; cs4 += b4; cs5 += b5;
            if (r < 16) {
                load6(rowbase + (r + 1) * 17, b0, b1, b2, b3, b4, b5);
                cs0 += b0; cs1 += b1; cs2 += b2; cs3 += b3; cs4 += b4; cs5 += b5;
            }
        }
        if (c0 == 0) cs0 = 0;                       // col -1
        if (c0 == 16) { cs2 = 0; cs3 = 0; cs4 = 0; cs5 = 0; }  // cols 17..20
        int o0 = cs0 + cs1 + cs2;
        int o1 = cs1 + cs2 + cs3;
        int o2 = cs2 + cs3 + cs4;
        int o3 = cs3 + cs4 + cs5;
        int i0 = r * 17 + c0;
        slab16[(i0 + 0) * 32 + p] = (short)o0;
        int a = o0 < 0 ? -o0 : o0; tmax = a > tmax ? a : tmax;
        if (c0 + 1 < 17) {
            slab16[(i0 + 1) * 32 + p] = (short)o1;
            a = o1 < 0 ? -o1 : o1; tmax = a > tmax ? a : tmax;
            slab16[(i0 + 2) * 32 + p] = (short)o2;
            a = o2 < 0 ? -o2 : o2; tmax = a > tmax ? a : tmax;
            slab16[(i0 + 3) * 32 + p] = (short)o3;
            a = o3 < 0 ? -o3 : o3; tmax = a > tmax ? a : tmax;
        }
    }

#pragma unroll
    for (int off = 32; off; off >>= 1) {
        int o = __shfl_down(tmax, off);
        tmax = o > tmax ? o : tmax;
    }
    if ((tid & 63) == 0) smax[tid >> 6] = tmax;
    __syncthreads();
    if (tid == 0) {
        int bm = smax[0];
#pragma unroll
        for (int i = 1; i < 4; ++i) bm = smax[i] > bm ? smax[i] : bm;
        atomicMax((int*)(cnt + 1), bm);
    }
}

// int8 MFMA GEMM with in-block LUT + channel-scalar prologue. (r14-r17 proven)
__launch_bounds__(256) __global__
void k_gemm(const short* __restrict__ pooled,
            const signed char* __restrict__ w_q8,
            const float* __restrict__ wsf_g, const float* __restrict__ bf_g,
            unsigned* cnt, float* __restrict__ out) {
    __shared__ char sW[2][12288];       // [192][64] i8, XOR-swizzled
    __shared__ char sX[2][5120];        // [80][64] i8 (hw rows), XOR-swizzled
    __shared__ unsigned char s_lut[2305];
    __shared__ float s_bint[192];
    __shared__ float s_scale[192];
    __shared__ float red[4];
    const int tid = threadIdx.x;
    const int b = blockIdx.z;
    const int hw0 = blockIdx.x * 80;
    const int L = tid & 63;
    const int wv = tid >> 6;
    const int wo = wv * 48;
    const char* pooled_b = (const char*)pooled;

    {
        const float s0 = fmaxf(__uint_as_float(cnt[0]) / QN_, 1e-8f);
        const float maxx2 = ((float)((const int*)cnt)[1] / 9.0f) * s0;
        const float s1 = fmaxf(maxx2 / QN_, 1e-8f);
        for (int i = tid; i < 2305; i += 256) {
            float p = (float)(i - 1152);
            float t = (p / 9.0f) * s0;
            float v = rintf(t / s1);
            v = fminf(fmaxf(v, -128.f), 127.f);
            s_lut[i] = (unsigned char)(signed char)(int)v;
        }
        if (tid < 192) {
            float wsf = wsf_g[tid];
            s_bint[tid] = rintf(bf_g[tid] / (wsf * s1));
            s_scale[tid] = wsf * s1;
        }
    }

    const int row0 = tid >> 3, ch0 = tid & 7;               // item = tid
    const int row1 = 32 + (tid >> 3), ch1 = tid & 7;        // item = 256+tid
    const int row2 = 64 + (tid >> 3), ch2 = tid & 7;        // item = 512+tid (tid<128)
    const bool act2 = tid < 128;

    uint4 xr0, xr1, xr2;

    auto stageW = [&](int kt, int buf) {
#pragma unroll
        for (int j = 0; j < 3; ++j) {
            int ldsoff = (wv * 3 + j) * 1024;
            const char* src = (const char*)w_q8 + kt * 12288 + SWZ(ldsoff + L * 16);
            __builtin_amdgcn_global_load_lds(
                (const __attribute__((address_space(1))) unsigned int*)src,
                (__attribute__((address_space(3))) unsigned int*)(&sW[buf][0] + ldsoff),
                16, 0, 0);
        }
    };
    auto ldx = [&](int kt, int row, int ch) -> uint4 {
        uint4 z; z.x = z.y = z.z = z.w = 0u;
        int hw = hw0 + row;
        if (hw >= HW_) return z;
        size_t slab = (size_t)(b * 24 + 2 * kt + (ch >> 2)) * SLAB_BYT;
        return *(const uint4*)(pooled_b + slab + hw * 64 + (ch & 3) * 16);
    };
    auto loadX = [&](int kt) {
        xr0 = ldx(kt, row0, ch0);
        xr1 = ldx(kt, row1, ch1);
        if (act2) xr2 = ldx(kt, row2, ch2);
    };
    auto pack8 = [&](const uint4& v) -> uint2 {
        unsigned c0 = s_lut[1152 + (short)(v.x)];
        unsigned c1 = s_lut[1152 + (short)(v.x >> 16)];
        unsigned c2 = s_lut[1152 + (short)(v.y)];
        unsigned c3 = s_lut[1152 + (short)(v.y >> 16)];
        unsigned c4 = s_lut[1152 + (short)(v.z)];
        unsigned c5 = s_lut[1152 + (short)(v.z >> 16)];
        unsigned c6 = s_lut[1152 + (short)(v.w)];
        unsigned c7 = s_lut[1152 + (short)(v.w >> 16)];
        uint2 r;
        r.x = c0 | (c1 << 8) | (c2 << 16) | (c3 << 24);
        r.y = c4 | (c5 << 8) | (c6 << 16) | (c7 << 24);
        return r;
    };
    auto writeX = [&](int buf) {
        *(uint2*)(&sX[buf][0] + SWZ(row0 * 64 + ch0 * 8)) = pack8(xr0);
        *(uint2*)(&sX[buf][0] + SWZ(row1 * 64 + ch1 * 8)) = pack8(xr1);
        if (act2) *(uint2*)(&sX[buf][0] + SWZ(row2 * 64 + ch2 * 8)) = pack8(xr2);
    };

    i32x4 acc[3][5] = {};

    stageW(0, 0);
    loadX(0);
    __syncthreads();   // s_lut/s_bint ready (also drains W(0))
    writeX(0);
    __syncthreads();   // buf0 ready

    for (int kt = 0; kt < 12; ++kt) {
        const int cur = kt & 1, nxt = cur ^ 1;
        if (kt < 11) {
            stageW(kt + 1, nxt);
            loadX(kt + 1);
        }
        i32x4 af[3], bfr[5];
#pragma unroll
        for (int m = 0; m < 3; ++m)
            af[m] = *(const i32x4*)(&sW[cur][0] +
                SWZ((wo + m * 16 + (L & 15)) * 64 + (L >> 4) * 16));
#pragma unroll
        for (int n = 0; n < 5; ++n)
            bfr[n] = *(const i32x4*)(&sX[cur][0] +
                SWZ((n * 16 + (L & 15)) * 64 + (L >> 4) * 16));
#pragma unroll
        for (int m = 0; m < 3; ++m)
#pragma unroll
            for (int n = 0; n < 5; ++n)
                acc[m][n] = __builtin_amdgcn_mfma_i32_16x16x64_i8(
                    af[m], bfr[n], acc[m][n], 0, 0, 0);
        if (kt < 11) writeX(nxt);
        __syncthreads();
    }

    float lmax = 0.f;
#pragma unroll
    for (int m = 0; m < 3; ++m) {
        int ob = wo + m * 16 + (L >> 4) * 4;
        float bi0 = s_bint[ob + 0], bi1 = s_bint[ob + 1];
        float bi2 = s_bint[ob + 2], bi3 = s_bint[ob + 3];
        float sc0 = s_scale[ob + 0], sc1 = s_scale[ob + 1];
        float sc2 = s_scale[ob + 2], sc3 = s_scale[ob + 3];
#pragma unroll
        for (int n = 0; n < 5; ++n) {
            int hw = hw0 + n * 16 + (L & 15);
            if (hw < HW_) {
                size_t base = ((size_t)b * O_ + ob) * HW_ + hw;
                float v0 = fmaxf(((float)acc[m][n][0] + bi0) * sc0, 0.f);
                float v1 = fmaxf(((float)acc[m][n][1] + bi1) * sc1, 0.f);
                float v2 = fmaxf(((float)acc[m][n][2] + bi2) * sc2, 0.f);
                float v3 = fmaxf(((float)acc[m][n][3] + bi3) * sc3, 0.f);
                out[base + 0 * HW_] = v0;
                out[base + 1 * HW_] = v1;
                out[base + 2 * HW_] = v2;
                out[base + 3 * HW_] = v3;
                lmax = fmaxf(fmaxf(fmaxf(v0, v1), fmaxf(v2, v3)), lmax);
            }
        }
    }
#pragma unroll
    for (int off = 32; off; off >>= 1) lmax = fmaxf(lmax, __shfl_down(lmax, off));
    if (L == 0) red[wv] = lmax;
    __syncthreads();
    if (tid == 0) {
        float bm = fmaxf(fmaxf(red[0], red[1]), fmaxf(red[2], red[3]));
        atomicMax(cnt + 2, __float_as_uint(bm));
    }
}

__global__ void k_quant_out(float* __restrict__ out, const unsigned* __restrict__ cnt) {
    const float s2 = fmaxf(__uint_as_float(cnt[2]) / QN_, 1e-8f);
    float4* o4 = (float4*)out;
    const int n4 = N_OUT / 4;
    for (int i = blockIdx.x * blockDim.x + threadIdx.x; i < n4;
         i += gridDim.x * blockDim.x) {
        float4 v = o4[i];
        v.x = fminf(fmaxf(rintf(v.x / s2), -128.f), 127.f) * s2;
        v.y = fminf(fmaxf(rintf(v.y / s2), -128.f), 127.f) * s2;
        v.z = fminf(fmaxf(rintf(v.z / s2), -128.f), 127.f) * s2;
        v.w = fminf(fmaxf(rintf(v.w / s2), -128.f), 127.f) * s2;
        o4[i] = v;
    }
    if (blockIdx.x == 0 && threadIdx.x == 0) out[N_OUT] = s2;
}

extern "C" void kernel_launch(void* const* d_in, const int* in_sizes, int n_in,
                              void* d_out, int out_size, void* d_ws, size_t ws_size,
                              hipStream_t stream) {
    const float* x      = (const float*)d_in[0];
    const float* conv_w = (const float*)d_in[1];
    const float* g      = (const float*)d_in[2];
    const float* beta   = (const float*)d_in[3];
    const float* mu     = (const float*)d_in[4];
    const float* var    = (const float*)d_in[5];
    float* out = (float*)d_out;

    char* wsb = (char*)d_ws;
    unsigned* cnt          = (unsigned*)wsb;
    float* wsf_g           = (float*)(wsb + 4096);
    float* bf_g            = (float*)(wsb + 5120);
    signed char* w_q8      = (signed char*)(wsb + 8192);
    short* pooled          = (short*)(wsb + (1u << 20));

    hipMemsetAsync(cnt, 0, 16, stream);
    k_pre<<<AB_BLOCKS + O_, 256, 0, stream>>>((const float4*)x, N_IN / 4, conv_w,
                                              g, beta, mu, var, w_q8, wsf_g, bf_g,
                                              cnt);
    k_quant<<<2048, 256, 0, stream>>>((const float4*)x, (char*)pooled, cnt);
    k_pool<<<3072, 256, 0, stream>>>(pooled, cnt);
    dim3 ggrid(4, 1, B_);
    k_gemm<<<ggrid, 256, 0, stream>>>(pooled, w_q8, wsf_g, bf_g, cnt, out);
    k_quant_out<<<2048, 256, 0, stream>>>(out, cnt);
}

// Round 19
// 125.826 us; speedup vs baseline: 1.2352x; 1.2352x over previous
//
#include <hip/hip_runtime.h>
#include <math.h>

#define B_    128
#define C_    768
#define O_    192
#define HW_   289
#define N_IN  (128*768*289)
#define N_OUT (128*192*289)
#define QN_   127.0f

// quant_pool: block = (b, kt32) slab of 32 planes; padded LDS [32][19][20] f32
#define SLAB_E   (32*289)           // 9248 elements per slab
#define SLAB_SH  9248               // shorts per pooled slab
#define SLAB_BYT 18496              // bytes per pooled slab
#define QP_LDS   (32*380)           // 12160 f32

#define AB_BLOCKS 2048              // absmax blocks in fused pre-kernel

typedef __attribute__((ext_vector_type(4))) int i32x4;

// XOR swizzle within a 64B row: flip 16B-chunk bits (4..5) by row bits (6..7). Involution.
#define SWZ(b) ((b) ^ ((((b) >> 6) & 3) << 4))

// ws layout:
//  0     : cnt[0]=absmax(x) bits, cnt[1]=max|pooled| int, cnt[2]=absmax(out) bits
//  4096  : f32 wsf_g[192]
//  5120  : f32 bf_g[192]
//  8192  : i8 w_q8 image, [kt64][o][64c] linear, 12*12288 B
//  1MiB  : i16 pooled[3072 slabs][289][32]

// Fused: blocks 0..2047 absmax(x); blocks 2048..2239 weight-quant (independent).
__global__ void k_pre(const float4* __restrict__ x4, int n4,
                      const float* __restrict__ conv_w,
                      const float* __restrict__ g,
                      const float* __restrict__ beta,
                      const float* __restrict__ mu,
                      const float* __restrict__ var,
                      signed char* __restrict__ w_q8,
                      float* __restrict__ wsf_g, float* __restrict__ bf_g,
                      unsigned* cnt) {
    if (blockIdx.x < AB_BLOCKS) {
        float m = 0.f;
        const int stride = AB_BLOCKS * blockDim.x;
        int i = blockIdx.x * blockDim.x + threadIdx.x;
        for (; i + stride < n4; i += 2 * stride) {
            float4 v = x4[i];
            float4 w = x4[i + stride];
            m = fmaxf(m, fmaxf(fmaxf(fabsf(v.x), fabsf(v.y)),
                               fmaxf(fabsf(v.z), fabsf(v.w))));
            m = fmaxf(m, fmaxf(fmaxf(fabsf(w.x), fabsf(w.y)),
                               fmaxf(fabsf(w.z), fabsf(w.w))));
        }
        if (i < n4) {
            float4 v = x4[i];
            m = fmaxf(m, fmaxf(fmaxf(fabsf(v.x), fabsf(v.y)),
                               fmaxf(fabsf(v.z), fabsf(v.w))));
        }
#pragma unroll
        for (int off = 32; off; off >>= 1) m = fmaxf(m, __shfl_down(m, off));
        __shared__ float sm[4];
        int lane = threadIdx.x & 63, wv = threadIdx.x >> 6;
        if (lane == 0) sm[wv] = m;
        __syncthreads();
        if (threadIdx.x == 0) {
            float bm = fmaxf(fmaxf(sm[0], sm[1]), fmaxf(sm[2], sm[3]));
            atomicMax(cnt + 0, __float_as_uint(bm));
        }
        return;
    }
    const int o = blockIdx.x - AB_BLOCKS;   // 0..191
    const float stdv = sqrtf(var[o] + 1e-5f);
    const float r = g[o] / stdv;
    const float* wo = conv_w + o * C_;
    float m = 0.f;
    for (int c = threadIdx.x; c < C_; c += 256) m = fmaxf(m, fabsf(wo[c] * r));
#pragma unroll
    for (int off = 32; off; off >>= 1) m = fmaxf(m, __shfl_down(m, off));
    __shared__ float sm2[4];
    __shared__ float swsf;
    int lane = threadIdx.x & 63, wv = threadIdx.x >> 6;
    if (lane == 0) sm2[wv] = m;
    __syncthreads();
    if (threadIdx.x == 0) {
        float bm = fmaxf(fmaxf(sm2[0], sm2[1]), fmaxf(sm2[2], sm2[3]));
        swsf = fmaxf(bm / QN_, 1e-8f);
    }
    __syncthreads();
    const float wsf = swsf;
    for (int c = threadIdx.x; c < C_; c += 256) {
        float wi = rintf(wo[c] * r / wsf);
        wi = fminf(fmaxf(wi, -128.f), 127.f);
        w_q8[(c >> 6) * 12288 + o * 64 + (c & 63)] = (signed char)(int)wi;
    }
    if (threadIdx.x == 0) {
        wsf_g[o] = wsf;
        bf_g[o] = beta[o] - g[o] * mu[o] / stdv;
    }
}

// Quantize + 3x3 zero-pad pooling. Block = (kt32, b): 32 planes. f32 LDS codes,
// border-only zeroing merged with quant scatter: one barrier. (r15/r17-proven)
__launch_bounds__(512) __global__
void k_quant_pool(const float* __restrict__ x, short* __restrict__ pooled,
                  unsigned* cnt) {
    __shared__ __align__(16) float fq[QP_LDS + 8];
    __shared__ int smax[8];
    const int tid = threadIdx.x;
    const int kt = blockIdx.x;          // 0..23
    const int b = blockIdx.z;           // 0..127
    const float s0 = fmaxf(__uint_as_float(cnt[0]) / QN_, 1e-8f);

    // zero border slots (91 per plane) + tail pad
    for (int i = tid; i < 32 * 91; i += 512) {
        int p = i / 91, rem = i - p * 91;
        int slot;
        if (rem < 20) slot = rem;                       // row 0
        else if (rem < 40) slot = 360 + (rem - 20);     // row 18
        else {
            int t = rem - 40;
            int rr = t / 3, cc = t - rr * 3;            // rows 1..17, cols {0,18,19}
            slot = (rr + 1) * 20 + (cc == 0 ? 0 : 17 + cc);
        }
        fq[p * 380 + slot] = 0.f;
    }
    if (tid < 8) fq[QP_LDS + tid] = 0.f;

    // quant scatter: interior slots (disjoint from borders)
    const float4* xg4 = (const float4*)(x + ((size_t)b * 768 + kt * 32) * HW_);
    for (int t = tid; t < SLAB_E / 4; t += 512) {
        float4 v = xg4[t];
        float q0 = rintf(v.x / s0);
        float q1 = rintf(v.y / s0);
        float q2 = rintf(v.z / s0);
        float q3 = rintf(v.w / s0);
        int e = 4 * t;
#pragma unroll
        for (int j = 0; j < 4; ++j) {
            float q = (j == 0) ? q0 : (j == 1) ? q1 : (j == 2) ? q2 : q3;
            int ej = e + j;
            int p = (ej * 29027) >> 23;            // ej/289
            int i2 = ej - p * 289;
            int r = (i2 * 3856) >> 16;             // i2/17
            int c = i2 - r * 17;
            fq[p * 380 + (r + 1) * 20 + (c + 1)] = q;
        }
    }
    __syncthreads();

    short* slab = pooled + (size_t)(b * 24 + kt) * SLAB_SH;
    int tmax = 0;
    for (int task = tid; task < 2720; task += 512) {
        int p = task & 31;
        int rt = task >> 5;                 // 0..84
        int r = (rt * 3277) >> 14;          // rt/5
        int t5 = rt - r * 5;
        int c0 = t5 * 4;
        const float* base = fq + p * 380 + r * 20 + c0;
        float4 a0 = *(const float4*)(base);
        float4 a1 = *(const float4*)(base + 4);
        float4 b0 = *(const float4*)(base + 20);
        float4 b1 = *(const float4*)(base + 24);
        float4 d0 = *(const float4*)(base + 40);
        float4 d1 = *(const float4*)(base + 44);
        float s0c = a0.x + b0.x + d0.x;
        float s1c = a0.y + b0.y + d0.y;
        float s2c = a0.z + b0.z + d0.z;
        float s3c = a0.w + b0.w + d0.w;
        float s4c = a1.x + b1.x + d1.x;
        float s5c = a1.y + b1.y + d1.y;
        int o0 = (int)(s0c + s1c + s2c);
        int o1 = (int)(s1c + s2c + s3c);
        int o2 = (int)(s2c + s3c + s4c);
        int o3 = (int)(s3c + s4c + s5c);
        int i0 = r * 17 + c0;
        slab[(i0 + 0) * 32 + p] = (short)o0;
        int a = o0 < 0 ? -o0 : o0; tmax = a > tmax ? a : tmax;
        if (c0 + 1 < 17) {
            slab[(i0 + 1) * 32 + p] = (short)o1;
            a = o1 < 0 ? -o1 : o1; tmax = a > tmax ? a : tmax;
            slab[(i0 + 2) * 32 + p] = (short)o2;
            a = o2 < 0 ? -o2 : o2; tmax = a > tmax ? a : tmax;
            slab[(i0 + 3) * 32 + p] = (short)o3;
            a = o3 < 0 ? -o3 : o3; tmax = a > tmax ? a : tmax;
        }
    }

#pragma unroll
    for (int off = 32; off; off >>= 1) {
        int o = __shfl_down(tmax, off);
        tmax = o > tmax ? o : tmax;
    }
    if ((tid & 63) == 0) smax[tid >> 6] = tmax;
    __syncthreads();
    if (tid == 0) {
        int bm = smax[0];
#pragma unroll
        for (int i = 1; i < 8; ++i) bm = smax[i] > bm ? smax[i] : bm;
        atomicMax((int*)(cnt + 1), bm);
    }
}

// int8 MFMA GEMM with in-block LUT + channel-scalar prologue. (r14/r15-proven)
__launch_bounds__(256) __global__
void k_gemm(const short* __restrict__ pooled,
            const signed char* __restrict__ w_q8,
            const float* __restrict__ wsf_g, const float* __restrict__ bf_g,
            unsigned* cnt, float* __restrict__ out) {
    __shared__ char sW[2][12288];       // [192][64] i8, XOR-swizzled
    __shared__ char sX[2][5120];        // [80][64] i8 (hw rows), XOR-swizzled
    __shared__ unsigned char s_lut[2305];
    __shared__ float s_bint[192];
    __shared__ float s_scale[192];
    __shared__ float red[4];
    const int tid = threadIdx.x;
    const int b = blockIdx.z;
    const int hw0 = blockIdx.x * 80;
    const int L = tid & 63;
    const int wv = tid >> 6;
    const int wo = wv * 48;
    const char* pooled_b = (const char*)pooled;

    {
        const float s0 = fmaxf(__uint_as_float(cnt[0]) / QN_, 1e-8f);
        const float maxx2 = ((float)((const int*)cnt)[1] / 9.0f) * s0;
        const float s1 = fmaxf(maxx2 / QN_, 1e-8f);
        for (int i = tid; i < 2305; i += 256) {
            float p = (float)(i - 1152);
            float t = (p / 9.0f) * s0;
            float v = rintf(t / s1);
            v = fminf(fmaxf(v, -128.f), 127.f);
            s_lut[i] = (unsigned char)(signed char)(int)v;
        }
        if (tid < 192) {
            float wsf = wsf_g[tid];
            s_bint[tid] = rintf(bf_g[tid] / (wsf * s1));
            s_scale[tid] = wsf * s1;
        }
    }

    const int row0 = tid >> 3, ch0 = tid & 7;               // item = tid
    const int row1 = 32 + (tid >> 3), ch1 = tid & 7;        // item = 256+tid
    const int row2 = 64 + (tid >> 3), ch2 = tid & 7;        // item = 512+tid (tid<128)
    const bool act2 = tid < 128;

    uint4 xr0, xr1, xr2;

    auto stageW = [&](int kt, int buf) {
#pragma unroll
        for (int j = 0; j < 3; ++j) {
            int ldsoff = (wv * 3 + j) * 1024;
            const char* src = (const char*)w_q8 + kt * 12288 + SWZ(ldsoff + L * 16);
            __builtin_amdgcn_global_load_lds(
                (const __attribute__((address_space(1))) unsigned int*)src,
                (__attribute__((address_space(3))) unsigned int*)(&sW[buf][0] + ldsoff),
                16, 0, 0);
        }
    };
    auto ldx = [&](int kt, int row, int ch) -> uint4 {
        uint4 z; z.x = z.y = z.z = z.w = 0u;
        int hw = hw0 + row;
        if (hw >= HW_) return z;
        size_t slab = (size_t)(b * 24 + 2 * kt + (ch >> 2)) * SLAB_BYT;
        return *(const uint4*)(pooled_b + slab + hw * 64 + (ch & 3) * 16);
    };
    auto loadX = [&](int kt) {
        xr0 = ldx(kt, row0, ch0);
        xr1 = ldx(kt, row1, ch1);
        if (act2) xr2 = ldx(kt, row2, ch2);
    };
    auto pack8 = [&](const uint4& v) -> uint2 {
        unsigned c0 = s_lut[1152 + (short)(v.x)];
        unsigned c1 = s_lut[1152 + (short)(v.x >> 16)];
        unsigned c2 = s_lut[1152 + (short)(v.y)];
        unsigned c3 = s_lut[1152 + (short)(v.y >> 16)];
        unsigned c4 = s_lut[1152 + (short)(v.z)];
        unsigned c5 = s_lut[1152 + (short)(v.z >> 16)];
        unsigned c6 = s_lut[1152 + (short)(v.w)];
        unsigned c7 = s_lut[1152 + (short)(v.w >> 16)];
        uint2 r;
        r.x = c0 | (c1 << 8) | (c2 << 16) | (c3 << 24);
        r.y = c4 | (c5 << 8) | (c6 << 16) | (c7 << 24);
        return r;
    };
    auto writeX = [&](int buf) {
        *(uint2*)(&sX[buf][0] + SWZ(row0 * 64 + ch0 * 8)) = pack8(xr0);
        *(uint2*)(&sX[buf][0] + SWZ(row1 * 64 + ch1 * 8)) = pack8(xr1);
        if (act2) *(uint2*)(&sX[buf][0] + SWZ(row2 * 64 + ch2 * 8)) = pack8(xr2);
    };

    i32x4 acc[3][5] = {};

    stageW(0, 0);
    loadX(0);
    __syncthreads();   // s_lut/s_bint ready (also drains W(0))
    writeX(0);
    __syncthreads();   // buf0 ready

    for (int kt = 0; kt < 12; ++kt) {
        const int cur = kt & 1, nxt = cur ^ 1;
        if (kt < 11) {
            stageW(kt + 1, nxt);
            loadX(kt + 1);
        }
        i32x4 af[3], bfr[5];
#pragma unroll
        for (int m = 0; m < 3; ++m)
            af[m] = *(const i32x4*)(&sW[cur][0] +
                SWZ((wo + m * 16 + (L & 15)) * 64 + (L >> 4) * 16));
#pragma unroll
        for (int n = 0; n < 5; ++n)
            bfr[n] = *(const i32x4*)(&sX[cur][0] +
                SWZ((n * 16 + (L & 15)) * 64 + (L >> 4) * 16));
#pragma unroll
        for (int m = 0; m < 3; ++m)
#pragma unroll
            for (int n = 0; n < 5; ++n)
                acc[m][n] = __builtin_amdgcn_mfma_i32_16x16x64_i8(
                    af[m], bfr[n], acc[m][n], 0, 0, 0);
        if (kt < 11) writeX(nxt);
        __syncthreads();
    }

    float lmax = 0.f;
#pragma unroll
    for (int m = 0; m < 3; ++m) {
        int ob = wo + m * 16 + (L >> 4) * 4;
        float bi0 = s_bint[ob + 0], bi1 = s_bint[ob + 1];
        float bi2 = s_bint[ob + 2], bi3 = s_bint[ob + 3];
        float sc0 = s_scale[ob + 0], sc1 = s_scale[ob + 1];
        float sc2 = s_scale[ob + 2], sc3 = s_scale[ob + 3];
#pragma unroll
        for (int n = 0; n < 5; ++n) {
            int hw = hw0 + n * 16 + (L & 15);
            if (hw < HW_) {
                size_t base = ((size_t)b * O_ + ob) * HW_ + hw;
                float v0 = fmaxf(((float)acc[m][n][0] + bi0) * sc0, 0.f);
                float v1 = fmaxf(((float)acc[m][n][1] + bi1) * sc1, 0.f);
                float v2 = fmaxf(((float)acc[m][n][2] + bi2) * sc2, 0.f);
                float v3 = fmaxf(((float)acc[m][n][3] + bi3) * sc3, 0.f);
                out[base + 0 * HW_] = v0;
                out[base + 1 * HW_] = v1;
                out[base + 2 * HW_] = v2;
                out[base + 3 * HW_] = v3;
                lmax = fmaxf(fmaxf(fmaxf(v0, v1), fmaxf(v2, v3)), lmax);
            }
        }
    }
#pragma unroll
    for (int off = 32; off; off >>= 1) lmax = fmaxf(lmax, __shfl_down(lmax, off));
    if (L == 0) red[wv] = lmax;
    __syncthreads();
    if (tid == 0) {
        float bm = fmaxf(fmaxf(red[0], red[1]), fmaxf(red[2], red[3]));
        atomicMax(cnt + 2, __float_as_uint(bm));
    }
}

__global__ void k_quant_out(float* __restrict__ out, const unsigned* __restrict__ cnt) {
    const float s2 = fmaxf(__uint_as_float(cnt[2]) / QN_, 1e-8f);
    float4* o4 = (float4*)out;
    const int n4 = N_OUT / 4;
    for (int i = blockIdx.x * blockDim.x + threadIdx.x; i < n4;
         i += gridDim.x * blockDim.x) {
        float4 v = o4[i];
        v.x = fminf(fmaxf(rintf(v.x / s2), -128.f), 127.f) * s2;
        v.y = fminf(fmaxf(rintf(v.y / s2), -128.f), 127.f) * s2;
        v.z = fminf(fmaxf(rintf(v.z / s2), -128.f), 127.f) * s2;
        v.w = fminf(fmaxf(rintf(v.w / s2), -128.f), 127.f) * s2;
        o4[i] = v;
    }
    if (blockIdx.x == 0 && threadIdx.x == 0) out[N_OUT] = s2;
}

extern "C" void kernel_launch(void* const* d_in, const int* in_sizes, int n_in,
                              void* d_out, int out_size, void* d_ws, size_t ws_size,
                              hipStream_t stream) {
    const float* x      = (const float*)d_in[0];
    const float* conv_w = (const float*)d_in[1];
    const float* g      = (const float*)d_in[2];
    const float* beta   = (const float*)d_in[3];
    const float* mu     = (const float*)d_in[4];
    const float* var    = (const float*)d_in[5];
    float* out = (float*)d_out;

    char* wsb = (char*)d_ws;
    unsigned* cnt          = (unsigned*)wsb;
    float* wsf_g           = (float*)(wsb + 4096);
    float* bf_g            = (float*)(wsb + 5120);
    signed char* w_q8      = (signed char*)(wsb + 8192);
    short* pooled          = (short*)(wsb + (1u << 20));

    hipMemsetAsync(cnt, 0, 16, stream);
    k_pre<<<AB_BLOCKS + O_, 256, 0, stream>>>((const float4*)x, N_IN / 4, conv_w,
                                              g, beta, mu, var, w_q8, wsf_g, bf_g,
                                              cnt);
    dim3 qgrid(24, 1, B_);
    k_quant_pool<<<qgrid, 512, 0, stream>>>(x, pooled, cnt);
    dim3 ggrid(4, 1, B_);
    k_gemm<<<ggrid, 256, 0, stream>>>(pooled, w_q8, wsf_g, bf_g, cnt, out);
    k_quant_out<<<2048, 256, 0, stream>>>(out, cnt);
}